// Round 1
// baseline (329.581 us; speedup 1.0000x reference)
//
#include <hip/hip_runtime.h>
#include <stdint.h>

typedef unsigned int u32;
typedef unsigned long long u64;

#define N8   130560   // (2176/8)*(3840/8)   = 272*480
#define N16  32640    // (2176/16)*(3840/16) = 136*240
#define N32  8160     // (2176/32)*(3840/32) = 68*120
#define NTOT 171360
#define TOPK 1000
#define NWORDS 16
#define NBINS 4096
#define BUCKET_SCALE 682.0f
#define LIST_CAP 2048
#define OUT_ELEMS 15000

// workspace layout (bytes)
#define OFF_HIST   0        // u32[4096]
#define OFF_META   16384    // u32[16]  meta[0]=boundary bucket B, meta[1]=list count (atomic)
#define OFF_LIST   16448    // u64[2048]
#define OFF_BOXES  32832    // f32[4000]  (16B aligned)
#define OFF_SCORES 48832    // f32[1000]
#define OFF_KPS    52832    // f32[10000]
#define OFF_VALID  92832    // u64[16]
#define OFF_KEEP   92960    // u64[16]
#define OFF_MASK   93088    // u64[1000*16]
#define WS_BYTES   221088
#define MEMSET_BYTES 16448  // hist + meta

__device__ __forceinline__ float load_logit(int i, const float* s8, const float* s16, const float* s32) {
  if (i < N8) return s8[i];
  if (i < N8 + N16) return s16[i - N8];
  return s32[i - N8 - N16];
}

__device__ __forceinline__ u32 bucket_of(float x) {
  u32 b = (u32)(x * BUCKET_SCALE);
  return b > (NBINS - 1) ? (NBINS - 1) : b;
}

// K1: histogram of positive logits over 4096 value-quantized buckets
__global__ void k_hist(const float* __restrict__ s8, const float* __restrict__ s16,
                       const float* __restrict__ s32, u32* __restrict__ hist) {
  int i = blockIdx.x * 256 + threadIdx.x;
  if (i >= NTOT) return;
  float x = load_logit(i, s8, s16, s32);
  if (x > 0.0f) atomicAdd(&hist[bucket_of(x)], 1u);
}

// K2: find boundary bucket B such that count(bucket > B) < TOPK <= count(bucket >= B).
// If fewer than TOPK positives exist, B = 0 (take all).
__global__ void k_findB(const u32* __restrict__ hist, u32* __restrict__ meta) {
  __shared__ u32 hloc[NBINS];
  __shared__ u32 csum[256];
  int t = threadIdx.x;
  u32 sum = 0;
  for (int k = 0; k < 16; ++k) { u32 v = hist[t * 16 + k]; hloc[t * 16 + k] = v; sum += v; }
  csum[t] = sum;
  __syncthreads();
  if (t == 0) {
    u32 cum = 0, B = 0;
    for (int ct = 255; ct >= 0; --ct) {
      if (cum + csum[ct] >= TOPK) {
        for (int b = ct * 16 + 15; b >= ct * 16; --b) {
          cum += hloc[b];
          if (cum >= TOPK) { B = (u32)b; break; }
        }
        break;
      }
      cum += csum[ct];
    }
    meta[0] = B;
  }
}

// K3: compact every candidate with bucket >= B into list as (logit_bits<<32)|~idx
__global__ void k_compact(const float* __restrict__ s8, const float* __restrict__ s16,
                          const float* __restrict__ s32,
                          u32* __restrict__ meta, u64* __restrict__ list) {
  int i = blockIdx.x * 256 + threadIdx.x;
  if (i >= NTOT) return;
  float x = load_logit(i, s8, s16, s32);
  if (x <= 0.0f) return;
  u32 b = bucket_of(x);
  if (b < meta[0]) return;
  u32 pos = atomicAdd(&meta[1], 1u);
  if (pos < LIST_CAP)
    list[pos] = ((u64)__float_as_uint(x) << 32) | (u64)(~(u32)i);
}

// K4: single-block bitonic sort (2048, descending) + decode top-1000 boxes/kps/scores
__global__ void __launch_bounds__(1024) k_sort_decode(
    const u64* __restrict__ list, const u32* __restrict__ meta,
    const float* __restrict__ bb8,  const float* __restrict__ kp8,
    const float* __restrict__ bb16, const float* __restrict__ kp16,
    const float* __restrict__ bb32, const float* __restrict__ kp32,
    float* __restrict__ sBoxes, float* __restrict__ sScores,
    float* __restrict__ sKps, u64* __restrict__ validWords) {
  __shared__ u64 s[2048];
  int t = threadIdx.x;
  u32 cnt = meta[1];
  if (cnt > LIST_CAP) cnt = LIST_CAP;
  for (int j = t; j < 2048; j += 1024) s[j] = (j < (int)cnt) ? list[j] : 0ull;
  __syncthreads();
  for (int k = 2; k <= 2048; k <<= 1) {
    for (int j = k >> 1; j > 0; j >>= 1) {
      for (int i = t; i < 2048; i += 1024) {
        int l = i ^ j;
        if (l > i) {
          u64 a = s[i], b = s[l];
          bool sw = ((i & k) == 0) ? (a < b) : (a > b);  // descending
          if (sw) { s[i] = b; s[l] = a; }
        }
      }
      __syncthreads();
    }
  }
  bool valid = false;
  if (t < TOPK) {
    u64 key = s[t];
    u32 sb = (u32)(key >> 32);
    valid = (sb != 0);
    float4 box = make_float4(0.f, 0.f, 0.f, 0.f);
    float kv[10];
    for (int j = 0; j < 10; ++j) kv[j] = 0.f;
    float sc = 0.0f;
    if (valid) {
      float x = __uint_as_float(sb);
      sc = (float)(1.0 / (1.0 + exp(-(double)x)));   // sigmoid in f64, round once
      u32 idx = ~((u32)key);
      int stride, p, fw;
      const float *bb, *kp;
      if (idx < N8)            { stride = 8;  fw = 480; p = (int)idx;              bb = bb8;  kp = kp8;  }
      else if (idx < N8 + N16) { stride = 16; fw = 240; p = (int)idx - N8;         bb = bb16; kp = kp16; }
      else                     { stride = 32; fw = 120; p = (int)idx - (N8 + N16); bb = bb32; kp = kp32; }
      int xq = p % fw, yq = p / fw;
      float cx = (float)(xq * stride), cy = (float)(yq * stride);
      float st = (float)stride;
      {
#pragma clang fp contract(off)
        float d0 = bb[4 * p + 0] * st;
        float d1 = bb[4 * p + 1] * st;
        float d2 = bb[4 * p + 2] * st;
        float d3 = bb[4 * p + 3] * st;
        box.x = cx - d0; box.y = cy - d1; box.z = cx + d2; box.w = cy + d3;
        for (int j = 0; j < 10; ++j)
          kv[j] = kp[10 * p + j] * st + ((j & 1) ? cy : cx);
      }
    }
    ((float4*)sBoxes)[t] = box;
    sScores[t] = sc;
    for (int j = 0; j < 10; ++j) sKps[10 * t + j] = kv[j];
  }
  u64 bal = __ballot(valid);
  if ((t & 63) == 0) validWords[t >> 6] = bal;
}

__device__ __forceinline__ bool iou_gt04(float4 a, float4 b) {
#pragma clang fp contract(off)
  float areaA = (a.z - a.x) * (a.w - a.y);
  float areaB = (b.z - b.x) * (b.w - b.y);
  float ltx = fmaxf(a.x, b.x);
  float lty = fmaxf(a.y, b.y);
  float rbx = fminf(a.z, b.z);
  float rby = fminf(a.w, b.w);
  float wx = rbx - ltx; wx = wx > 0.0f ? wx : 0.0f;
  float wy = rby - lty; wy = wy > 0.0f ? wy : 0.0f;
  float inter = wx * wy;
  float un = areaA + areaB - inter;
  un = un > 1e-9f ? un : 1e-9f;
  return (inter / un) > 0.4f;
}

// K5: suppression bitmask: mask[i][w] bit b set iff j=w*64+b > i and IoU(i,j) > 0.4
__global__ void k_iou_mask(const float* __restrict__ sBoxes, u64* __restrict__ mask) {
  __shared__ float4 boxes[TOPK];
  int t = threadIdx.x;
  for (int r = t; r < TOPK; r += 256) boxes[r] = ((const float4*)sBoxes)[r];
  __syncthreads();
  int task = blockIdx.x * 256 + t;
  if (task >= TOPK * NWORDS) return;
  int i = task >> 4, w = task & 15;
  float4 a = boxes[i];
  u64 bits = 0;
  int base = w * 64;
  int j0 = base > (i + 1) ? base : (i + 1);
  int j1 = (base + 64) < TOPK ? (base + 64) : TOPK;
  for (int j = j0; j < j1; ++j) {
    if (iou_gt04(a, boxes[j])) bits |= 1ull << (j - base);
  }
  mask[(u64)i * NWORDS + w] = bits;
}

// K6: exact greedy NMS, single wave. 16 chunks of 64 rows; intra-chunk resolved by a
// 64-step shfl chain in registers; inter-chunk suppression recomputed per chunk with
// 64 independent (latency-hidden) loads per prior chunk + wave OR-reduce.
__global__ void k_nms(const u64* __restrict__ mask, const u64* __restrict__ validWords,
                      u64* __restrict__ keepWords) {
  int lane = threadIdx.x;  // 64 threads = 1 wave
  __shared__ u64 keepLds[NWORDS];
  for (int c = 0; c < NWORDS; ++c) {
    u64 acc = 0;
    for (int p = 0; p < c; ++p) {
      u64 kw = keepLds[p];
      u64 m = mask[(u64)(p * 64 + lane) * NWORDS + c];  // unconditional: pipelined
      if ((kw >> lane) & 1ull) acc |= m;
    }
    for (int off = 32; off > 0; off >>= 1) acc |= __shfl_xor(acc, off);
    int row = c * 64 + lane;
    u64 r = (row < TOPK) ? mask[(u64)row * NWORDS + c] : 0ull;
    u64 alive = validWords[c] & ~acc;   // uniform across lanes
    for (int i = 0; i < 64; ++i) {
      if ((alive >> i) & 1ull) {        // uniform branch
        u64 ri = __shfl(r, i);
        alive &= ~ri;                   // diag bit is 0 (mask has j>i only)
      }
    }
    if (lane == 0) { keepLds[c] = alive; keepWords[c] = alive; }
    __syncthreads();
  }
}

// K7: apply keep mask, write concatenated outputs [boxes 4000 | scores 1000 | kps 10000]
__global__ void k_finalize(const float* __restrict__ sBoxes, const float* __restrict__ sScores,
                           const float* __restrict__ sKps, const u64* __restrict__ keepWords,
                           float* __restrict__ out) {
  int o = blockIdx.x * 256 + threadIdx.x;
  if (o >= OUT_ELEMS) return;
  int row; float v;
  if (o < 4000)      { row = o >> 2;       v = sBoxes[o]; }
  else if (o < 5000) { row = o - 4000;     v = sScores[row]; }
  else               { int q = o - 5000; row = q / 10; v = sKps[q]; }
  u64 kw = keepWords[row >> 6];
  out[o] = ((kw >> (row & 63)) & 1ull) ? v : 0.0f;
}

extern "C" void kernel_launch(void* const* d_in, const int* in_sizes, int n_in,
                              void* d_out, int out_size, void* d_ws, size_t ws_size,
                              hipStream_t stream) {
  const float* s8   = (const float*)d_in[1];
  const float* bb8  = (const float*)d_in[2];
  const float* kp8  = (const float*)d_in[3];
  const float* s16  = (const float*)d_in[4];
  const float* bb16 = (const float*)d_in[5];
  const float* kp16 = (const float*)d_in[6];
  const float* s32  = (const float*)d_in[7];
  const float* bb32 = (const float*)d_in[8];
  const float* kp32 = (const float*)d_in[9];

  char* ws = (char*)d_ws;
  u32* hist       = (u32*)(ws + OFF_HIST);
  u32* meta       = (u32*)(ws + OFF_META);
  u64* list       = (u64*)(ws + OFF_LIST);
  float* sBoxes   = (float*)(ws + OFF_BOXES);
  float* sScores  = (float*)(ws + OFF_SCORES);
  float* sKps     = (float*)(ws + OFF_KPS);
  u64* validWords = (u64*)(ws + OFF_VALID);
  u64* keepWords  = (u64*)(ws + OFF_KEEP);
  u64* mask       = (u64*)(ws + OFF_MASK);

  hipMemsetAsync(ws, 0, MEMSET_BYTES, stream);

  int nb = (NTOT + 255) / 256;
  k_hist<<<nb, 256, 0, stream>>>(s8, s16, s32, hist);
  k_findB<<<1, 256, 0, stream>>>(hist, meta);
  k_compact<<<nb, 256, 0, stream>>>(s8, s16, s32, meta, list);
  k_sort_decode<<<1, 1024, 0, stream>>>(list, meta, bb8, kp8, bb16, kp16, bb32, kp32,
                                        sBoxes, sScores, sKps, validWords);
  k_iou_mask<<<(TOPK * NWORDS + 255) / 256, 256, 0, stream>>>(sBoxes, mask);
  k_nms<<<1, 64, 0, stream>>>(mask, validWords, keepWords);
  k_finalize<<<(OUT_ELEMS + 255) / 256, 256, 0, stream>>>(sBoxes, sScores, sKps, keepWords,
                                                          (float*)d_out);
}

// Round 2
// 239.997 us; speedup vs baseline: 1.3733x; 1.3733x over previous
//
#include <hip/hip_runtime.h>
#include <stdint.h>

typedef unsigned int u32;
typedef unsigned long long u64;

#define N8   130560   // (2176/8)*(3840/8)   = 272*480
#define N16  32640    // (2176/16)*(3840/16) = 136*240
#define N32  8160     // (2176/32)*(3840/32) = 68*120
#define NTOT 171360
#define NTOT4 42840   // NTOT/4 (all level sizes divisible by 4)
#define TOPK 1000
#define NWORDS 16
#define NBINS 4096
#define BUCKET_SCALE 682.0f
#define LIST_CAP 2048
#define OUT_ELEMS 15000

// workspace layout (bytes)
#define OFF_HIST   0        // u32[4096]
#define OFF_META   16384    // u32[16]  meta[0]=B, meta[1]=list count, meta[2]=block counter
#define OFF_NZ     16448    // u64[16]  rows with nonzero suppression mask
#define OFF_LIST   16576    // u64[2048]
#define OFF_BOXES  32960    // f32[4000]  (16B aligned)
#define OFF_SCORES 48960    // f32[1000]
#define OFF_KPS    52960    // f32[10000]
#define OFF_VALID  92960    // u64[16]
#define OFF_KEEP   93088    // u64[16]
#define OFF_MASK   93216    // u64[1000*16]
#define MEMSET_BYTES 16576  // hist + meta + nz

__device__ __forceinline__ u32 bucket_of(float x) {
  u32 b = (u32)(x * BUCKET_SCALE);
  return b > (NBINS - 1) ? (NBINS - 1) : b;
}

__device__ __forceinline__ float4 load_logit4(int v, const float* s8, const float* s16,
                                              const float* s32) {
  int e = v * 4;
  if (e < N8) return ((const float4*)s8)[v];
  if (e < N8 + N16) return ((const float4*)s16)[v - N8 / 4];
  return ((const float4*)s32)[v - (N8 + N16) / 4];
}

// K1: histogram of positive logits (float4 loads) + fused findB in the last block.
// B = boundary bucket: count(bucket >= B) >= TOPK > count(bucket > B); 0 if < TOPK positives.
__global__ void k_hist_findB(const float* __restrict__ s8, const float* __restrict__ s16,
                             const float* __restrict__ s32, u32* __restrict__ hist,
                             u32* __restrict__ meta) {
  int v = blockIdx.x * 256 + threadIdx.x;
  if (v < NTOT4) {
    float4 x = load_logit4(v, s8, s16, s32);
    if (x.x > 0.0f) atomicAdd(&hist[bucket_of(x.x)], 1u);
    if (x.y > 0.0f) atomicAdd(&hist[bucket_of(x.y)], 1u);
    if (x.z > 0.0f) atomicAdd(&hist[bucket_of(x.z)], 1u);
    if (x.w > 0.0f) atomicAdd(&hist[bucket_of(x.w)], 1u);
  }
  __threadfence();
  __shared__ int isLast;
  if (threadIdx.x == 0)
    isLast = (atomicAdd(&meta[2], 1u) == gridDim.x - 1) ? 1 : 0;
  __syncthreads();
  if (!isLast) return;

  // last block: findB over the completed histogram (atomic loads: device-coherent)
  __shared__ u32 hloc[NBINS];
  __shared__ u32 csum[256];
  int t = threadIdx.x;
  u32 sum = 0;
  for (int k = 0; k < 16; ++k) {
    u32 val = atomicAdd(&hist[t * 16 + k], 0u);
    hloc[t * 16 + k] = val;
    sum += val;
  }
  csum[t] = sum;
  __syncthreads();
  if (t == 0) {
    u32 cum = 0, B = 0;
    for (int ct = 255; ct >= 0; --ct) {
      if (cum + csum[ct] >= TOPK) {
        for (int b = ct * 16 + 15; b >= ct * 16; --b) {
          cum += hloc[b];
          if (cum >= TOPK) { B = (u32)b; break; }
        }
        break;
      }
      cum += csum[ct];
    }
    meta[0] = B;
  }
}

// K2: compact every candidate with bucket >= B into list as (logit_bits<<32)|~idx
__global__ void k_compact(const float* __restrict__ s8, const float* __restrict__ s16,
                          const float* __restrict__ s32,
                          u32* __restrict__ meta, u64* __restrict__ list) {
  int v = blockIdx.x * 256 + threadIdx.x;
  if (v >= NTOT4) return;
  float4 x = load_logit4(v, s8, s16, s32);
  u32 B = meta[0];
  float c[4] = {x.x, x.y, x.z, x.w};
#pragma unroll
  for (int j = 0; j < 4; ++j) {
    float xx = c[j];
    if (xx > 0.0f && bucket_of(xx) >= B) {
      u32 pos = atomicAdd(&meta[1], 1u);
      if (pos < LIST_CAP) {
        u32 idx = (u32)(v * 4 + j);
        list[pos] = ((u64)__float_as_uint(xx) << 32) | (u64)(~idx);
      }
    }
  }
}

// K3: single-block bitonic sort (2048, descending) + decode top-1000 boxes/kps/scores
__global__ void __launch_bounds__(1024) k_sort_decode(
    const u64* __restrict__ list, const u32* __restrict__ meta,
    const float* __restrict__ bb8,  const float* __restrict__ kp8,
    const float* __restrict__ bb16, const float* __restrict__ kp16,
    const float* __restrict__ bb32, const float* __restrict__ kp32,
    float* __restrict__ sBoxes, float* __restrict__ sScores,
    float* __restrict__ sKps, u64* __restrict__ validWords) {
  __shared__ u64 s[2048];
  int t = threadIdx.x;
  u32 cnt = meta[1];
  if (cnt > LIST_CAP) cnt = LIST_CAP;
  for (int j = t; j < 2048; j += 1024) s[j] = (j < (int)cnt) ? list[j] : 0ull;
  __syncthreads();
  for (int k = 2; k <= 2048; k <<= 1) {
    for (int j = k >> 1; j > 0; j >>= 1) {
      for (int i = t; i < 2048; i += 1024) {
        int l = i ^ j;
        if (l > i) {
          u64 a = s[i], b = s[l];
          bool sw = ((i & k) == 0) ? (a < b) : (a > b);  // descending
          if (sw) { s[i] = b; s[l] = a; }
        }
      }
      __syncthreads();
    }
  }
  bool valid = false;
  if (t < TOPK) {
    u64 key = s[t];
    u32 sb = (u32)(key >> 32);
    valid = (sb != 0);
    float4 box = make_float4(0.f, 0.f, 0.f, 0.f);
    float kv[10];
    for (int j = 0; j < 10; ++j) kv[j] = 0.f;
    float sc = 0.0f;
    if (valid) {
      float x = __uint_as_float(sb);
      sc = (float)(1.0 / (1.0 + exp(-(double)x)));   // sigmoid in f64, round once
      u32 idx = ~((u32)key);
      int stride, p, fw;
      const float *bb, *kp;
      if (idx < N8)            { stride = 8;  fw = 480; p = (int)idx;              bb = bb8;  kp = kp8;  }
      else if (idx < N8 + N16) { stride = 16; fw = 240; p = (int)idx - N8;         bb = bb16; kp = kp16; }
      else                     { stride = 32; fw = 120; p = (int)idx - (N8 + N16); bb = bb32; kp = kp32; }
      int xq = p % fw, yq = p / fw;
      float cx = (float)(xq * stride), cy = (float)(yq * stride);
      float st = (float)stride;
      {
#pragma clang fp contract(off)
        float d0 = bb[4 * p + 0] * st;
        float d1 = bb[4 * p + 1] * st;
        float d2 = bb[4 * p + 2] * st;
        float d3 = bb[4 * p + 3] * st;
        box.x = cx - d0; box.y = cy - d1; box.z = cx + d2; box.w = cy + d3;
        for (int j = 0; j < 10; ++j)
          kv[j] = kp[10 * p + j] * st + ((j & 1) ? cy : cx);
      }
    }
    ((float4*)sBoxes)[t] = box;
    sScores[t] = sc;
    for (int j = 0; j < 10; ++j) sKps[10 * t + j] = kv[j];
  }
  u64 bal = __ballot(valid);
  if ((t & 63) == 0) validWords[t >> 6] = bal;
}

__device__ __forceinline__ bool iou_gt04(float4 a, float4 b) {
#pragma clang fp contract(off)
  float areaA = (a.z - a.x) * (a.w - a.y);
  float areaB = (b.z - b.x) * (b.w - b.y);
  float ltx = fmaxf(a.x, b.x);
  float lty = fmaxf(a.y, b.y);
  float rbx = fminf(a.z, b.z);
  float rby = fminf(a.w, b.w);
  float wx = rbx - ltx; wx = wx > 0.0f ? wx : 0.0f;
  float wy = rby - lty; wy = wy > 0.0f ? wy : 0.0f;
  float inter = wx * wy;
  float un = areaA + areaB - inter;
  un = un > 1e-9f ? un : 1e-9f;
  return (inter / un) > 0.4f;
}

// K4: suppression bitmask (bit b of mask[i][w] set iff j=w*64+b > i and IoU>0.4)
// plus nz bitmap of rows whose mask is nonzero (the only rows greedy NMS must visit).
__global__ void k_iou_mask(const float* __restrict__ sBoxes, u64* __restrict__ mask,
                           u64* __restrict__ nzWords) {
  __shared__ float4 boxes[TOPK];
  int t = threadIdx.x;
  for (int r = t; r < TOPK; r += 256) boxes[r] = ((const float4*)sBoxes)[r];
  __syncthreads();
  int task = blockIdx.x * 256 + t;
  if (task >= TOPK * NWORDS) return;
  int i = task >> 4, w = task & 15;
  float4 a = boxes[i];
  u64 bits = 0;
  int base = w * 64;
  int j0 = base > (i + 1) ? base : (i + 1);
  int j1 = (base + 64) < TOPK ? (base + 64) : TOPK;
  for (int j = j0; j < j1; ++j) {
    if (iou_gt04(a, boxes[j])) bits |= 1ull << (j - base);
  }
  mask[(u64)i * NWORDS + w] = bits;
  if (bits) atomicOr(&nzWords[i >> 6], 1ull << (i & 63));
}

// K5: exact greedy NMS over only the nonzero-mask rows. Single wave.
// Rows with empty suppression sets cannot change the removed set -> skipping is exact.
__global__ void k_nms(const u64* __restrict__ mask, const u64* __restrict__ validWords,
                      const u64* __restrict__ nzWords, u64* __restrict__ keepWords) {
  int lane = threadIdx.x;  // 64 threads = 1 wave; lane<16 owns removed-word `lane`
  u64 remv = 0;
  u64 vw = (lane < NWORDS) ? validWords[lane] : 0ull;
  for (int c = 0; c < NWORDS; ++c) {
    u64 nzc = nzWords[c] & __shfl(vw, c);   // candidate suppressor rows, uniform
    while (nzc) {
      int b = __builtin_ctzll(nzc);
      nzc &= nzc - 1;
      u64 remc = __shfl(remv, c);           // current removed word c
      if (!((remc >> b) & 1ull)) {          // row alive -> apply its suppression row
        int i = c * 64 + b;
        u64 m = (lane < NWORDS) ? mask[(u64)i * NWORDS + lane] : 0ull;
        remv |= m;
      }
    }
  }
  if (lane < NWORDS) keepWords[lane] = vw & ~remv;
}

// K6: apply keep mask, write concatenated outputs [boxes 4000 | scores 1000 | kps 10000]
__global__ void k_finalize(const float* __restrict__ sBoxes, const float* __restrict__ sScores,
                           const float* __restrict__ sKps, const u64* __restrict__ keepWords,
                           float* __restrict__ out) {
  int o = blockIdx.x * 256 + threadIdx.x;
  if (o >= OUT_ELEMS) return;
  int row; float v;
  if (o < 4000)      { row = o >> 2;       v = sBoxes[o]; }
  else if (o < 5000) { row = o - 4000;     v = sScores[row]; }
  else               { int q = o - 5000; row = q / 10; v = sKps[q]; }
  u64 kw = keepWords[row >> 6];
  out[o] = ((kw >> (row & 63)) & 1ull) ? v : 0.0f;
}

extern "C" void kernel_launch(void* const* d_in, const int* in_sizes, int n_in,
                              void* d_out, int out_size, void* d_ws, size_t ws_size,
                              hipStream_t stream) {
  const float* s8   = (const float*)d_in[1];
  const float* bb8  = (const float*)d_in[2];
  const float* kp8  = (const float*)d_in[3];
  const float* s16  = (const float*)d_in[4];
  const float* bb16 = (const float*)d_in[5];
  const float* kp16 = (const float*)d_in[6];
  const float* s32  = (const float*)d_in[7];
  const float* bb32 = (const float*)d_in[8];
  const float* kp32 = (const float*)d_in[9];

  char* ws = (char*)d_ws;
  u32* hist       = (u32*)(ws + OFF_HIST);
  u32* meta       = (u32*)(ws + OFF_META);
  u64* nzWords    = (u64*)(ws + OFF_NZ);
  u64* list       = (u64*)(ws + OFF_LIST);
  float* sBoxes   = (float*)(ws + OFF_BOXES);
  float* sScores  = (float*)(ws + OFF_SCORES);
  float* sKps     = (float*)(ws + OFF_KPS);
  u64* validWords = (u64*)(ws + OFF_VALID);
  u64* keepWords  = (u64*)(ws + OFF_KEEP);
  u64* mask       = (u64*)(ws + OFF_MASK);

  hipMemsetAsync(ws, 0, MEMSET_BYTES, stream);

  int nbv = (NTOT4 + 255) / 256;  // 168
  k_hist_findB<<<nbv, 256, 0, stream>>>(s8, s16, s32, hist, meta);
  k_compact<<<nbv, 256, 0, stream>>>(s8, s16, s32, meta, list);
  k_sort_decode<<<1, 1024, 0, stream>>>(list, meta, bb8, kp8, bb16, kp16, bb32, kp32,
                                        sBoxes, sScores, sKps, validWords);
  k_iou_mask<<<(TOPK * NWORDS + 255) / 256, 256, 0, stream>>>(sBoxes, mask, nzWords);
  k_nms<<<1, 64, 0, stream>>>(mask, validWords, nzWords, keepWords);
  k_finalize<<<(OUT_ELEMS + 255) / 256, 256, 0, stream>>>(sBoxes, sScores, sKps, keepWords,
                                                          (float*)d_out);
}